// Round 2
// baseline (173.336 us; speedup 1.0000x reference)
//
#include <hip/hip_runtime.h>
#include <hip/hip_cooperative_groups.h>
#include <math.h>

namespace cg = cooperative_groups;

#define B_SZ 1024
#define C_SZ 1000
#define H_SZ 512

// ws layout (bytes):
//   [0,      4096)   int      jv[1024]       argmax index per batch row
//   [4096,   8192)   float    ymax[1024]     row max of y
//   [8192,  12288)   float    wnorm[1000]    ||w_c||^2 (fp32)
//   [16384,  81920)  float    part[16][1024] per-bx-strip row maxes
//   [524288,+1MB)    short    wbf[1000*512]  bf16 copy of w

typedef __attribute__((ext_vector_type(8))) short bf16x8;
typedef __attribute__((ext_vector_type(4))) float f32x4;

#define KC 128          // k elements per chunk
#define RS 136          // LDS row stride in shorts (+8 pad: 2-way = free)

// ---------------------------------------------------------------------------
// Single cooperative kernel, 256 blocks x 256 threads (1 block/CU, all
// co-resident). Replaces the former 3-launch pipeline; two grid.sync()s
// replace two kernel-boundary drain+launch gaps.
//
// Phase A: blocks 0..249: wnorm + f32->bf16 of 4 w-rows (1 wave/row).
//          ALL blocks: argmax/max/copy of 4 y-rows (1 wave/row, shuffle-only).
// Phase B: former K2 — gathered bf16 MFMA GEMM + fused epilogue.
//          A operand whole-K in VGPRs (no cross-wave reuse -> no LDS);
//          B tile LDS-staged in 4 K-chunks, register-prefetched 1 ahead.
// Phase C: former K3 — per-block reduce of its 4 rows' 16 strip partials.
__global__ __launch_bounds__(256) void k_fused(
    const float* __restrict__ y, const float* __restrict__ w,
    const float* __restrict__ eps_p, const float* __restrict__ lip_p,
    int* __restrict__ jv, float* __restrict__ ymax,
    float* __restrict__ wnorm, short* __restrict__ wbf,
    float* __restrict__ part, float* __restrict__ out) {
    cg::grid_group grid = cg::this_grid();

    __shared__ __align__(16) short Bs[64 * RS];
    __shared__ float snj[64];
    __shared__ float sym[64];

    const int blk = blockIdx.x;
    const int t = threadIdx.x;
    const int wv = t >> 6, lane = t & 63;

    // ---------------- Phase A1: w convert + wnorm (blocks 0..249) ----------
    if (blk < 250) {
        const int c = blk * 4 + wv;
        const float* row = w + c * H_SZ;
        float4 a = *(const float4*)(row + lane * 8);
        float4 b = *(const float4*)(row + lane * 8 + 4);
        float f[8] = {a.x, a.y, a.z, a.w, b.x, b.y, b.z, b.w};
        unsigned short u[8];
        float s = 0.f;
#pragma unroll
        for (int i = 0; i < 8; ++i) {
            s += f[i] * f[i];
            unsigned v = __float_as_uint(f[i]);
            v += 0x7fffu + ((v >> 16) & 1u);  // RNE
            u[i] = (unsigned short)(v >> 16);
        }
        uint4 pk;
        pk.x = (unsigned)u[0] | ((unsigned)u[1] << 16);
        pk.y = (unsigned)u[2] | ((unsigned)u[3] << 16);
        pk.z = (unsigned)u[4] | ((unsigned)u[5] << 16);
        pk.w = (unsigned)u[6] | ((unsigned)u[7] << 16);
        *(uint4*)(wbf + c * H_SZ + lane * 8) = pk;
#pragma unroll
        for (int off = 32; off; off >>= 1) s += __shfl_down(s, off, 64);
        if (lane == 0) wnorm[c] = s;
    }

    // ---------------- Phase A2: y argmax/max + copy (all blocks, 4 rows) ---
    {
        const int b = blk * 4 + wv;
        const float* yrow = y + b * C_SZ;
        float* orow = out + b * (C_SZ + 1);
        float best = -INFINITY;
        int bidx = 0x7fffffff;
#pragma unroll
        for (int p = 0; p < 4; ++p) {
            const int idx = lane + p * 64;  // float4 index, 0..249 valid
            if (idx < 250) {
                float4 v = *(const float4*)(yrow + idx * 4);
                float e[4] = {v.x, v.y, v.z, v.w};
#pragma unroll
                for (int i = 0; i < 4; ++i) {
                    orow[idx * 4 + i] = e[i];
                    if (e[i] > best) { best = e[i]; bidx = idx * 4 + i; }
                }
            }
        }
#pragma unroll
        for (int off = 32; off; off >>= 1) {
            float ov = __shfl_down(best, off, 64);
            int oi = __shfl_down(bidx, off, 64);
            if (ov > best || (ov == best && oi < bidx)) { best = ov; bidx = oi; }
        }
        if (lane == 0) { jv[b] = bidx; ymax[b] = best; }
    }

    __threadfence();  // cross-XCD visibility of wbf/jv/ymax/wnorm
    grid.sync();

    // ---------------- Phase B: gathered MFMA GEMM + fused epilogue ---------
    const int bx = blk & 15, by = blk >> 4;
    const int b0 = by * 64, c0 = bx * 64;

    if (t < 64) {
        int j = jv[b0 + t];
        snj[t] = wnorm[j];
        sym[t] = ymax[b0 + t];
    }

    const int col = lane & 15, quad = lane >> 4;

    // A: whole-K preload into registers. A-frag layout (verified prior
    // session): lane holds row (wv*16+col), 8 contiguous shorts at
    // k = ks*32 + quad*8. areg[k16] covers k16*32 .. +32.
    const int ja = jv[b0 + wv * 16 + col];
    const short* ag = wbf + ja * H_SZ + quad * 8;
    bf16x8 areg[16];
#pragma unroll
    for (int k16 = 0; k16 < 16; ++k16)
        areg[k16] = *(const bf16x8*)(ag + k16 * 32);

    // B: LDS staging, 4 threads per row, 4 passes of 16B
    const int srow = t >> 2;       // 0..63
    const int sseg = t & 3;
    int crow = c0 + srow; if (crow > C_SZ - 1) crow = C_SZ - 1;
    const short* bgsrc = wbf + crow * H_SZ;

    uint4 pb[4];
#pragma unroll
    for (int p = 0; p < 4; ++p)
        pb[p] = *(const uint4*)(bgsrc + (sseg + p * 4) * 8);

    const short* brd = &Bs[col * RS + quad * 8];

    f32x4 acc[4] = {{0.f, 0.f, 0.f, 0.f},
                    {0.f, 0.f, 0.f, 0.f},
                    {0.f, 0.f, 0.f, 0.f},
                    {0.f, 0.f, 0.f, 0.f}};

#pragma unroll   // must unroll: areg[ch*4+ks] needs compile-time indices
    for (int ch = 0; ch < 4; ++ch) {
#pragma unroll
        for (int p = 0; p < 4; ++p)
            *(uint4*)&Bs[srow * RS + (sseg + p * 4) * 8] = pb[p];
        __syncthreads();
        if (ch < 3) {
            const int gbase = (ch + 1) * KC;
#pragma unroll
            for (int p = 0; p < 4; ++p)
                pb[p] = *(const uint4*)(bgsrc + gbase + (sseg + p * 4) * 8);
        }
#pragma unroll
        for (int ks = 0; ks < 4; ++ks) {
            bf16x8 af = areg[ch * 4 + ks];
#pragma unroll
            for (int ct = 0; ct < 4; ++ct) {
                bf16x8 bf = *(const bf16x8*)(brd + ct * 16 * RS + ks * 32);
                acc[ct] =
                    __builtin_amdgcn_mfma_f32_16x16x32_bf16(af, bf, acc[ct], 0, 0, 0);
            }
        }
        __syncthreads();
    }

    // Epilogue. C/D layout: col=lane&15, row=quad*4+reg.
    const float eps = *eps_p;
    const float L = *lip_p;
    const float L2 = L * L;
    float rmax[4];
#pragma unroll
    for (int i = 0; i < 4; ++i) {
        const int br = wv * 16 + quad * 4 + i;
        const int b = b0 + br;
        const float nj = snj[br];
        const float ym = sym[br];
        float m = -INFINITY;
#pragma unroll
        for (int ct = 0; ct < 4; ++ct) {
            const int cc = c0 + ct * 16 + col;
            if (cc < C_SZ) {
                const float yv = y[b * C_SZ + cc];
                const float nc = wnorm[cc];
                const float sq = L2 * (nj + nc - 2.0f * acc[ct][i]);
                const float K = sq > 0.f ? sqrtf(sq) : 0.f;
                const float cand = (yv == ym) ? -INFINITY : yv + eps * K;
                m = fmaxf(m, cand);
            }
        }
        rmax[i] = m;
    }
#pragma unroll
    for (int off = 8; off; off >>= 1)
#pragma unroll
        for (int i = 0; i < 4; ++i)
            rmax[i] = fmaxf(rmax[i], __shfl_xor(rmax[i], off, 64));
    if (col == 0) {
        float* slice = part + bx * B_SZ;
#pragma unroll
        for (int i = 0; i < 4; ++i)
            slice[b0 + wv * 16 + quad * 4 + i] = rmax[i];
    }

    __threadfence();  // cross-XCD visibility of part
    grid.sync();

    // ---------------- Phase C: final reduce (4 rows per block) -------------
    if (t < 64) {
        const int row = blk * 4 + (t >> 4);
        const int strip = t & 15;
        float v = part[strip * B_SZ + row];
#pragma unroll
        for (int off = 8; off; off >>= 1)
            v = fmaxf(v, __shfl_xor(v, off, 64));
        if (strip == 0) out[row * (C_SZ + 1) + C_SZ] = v;
    }
}

// ---------------------------------------------------------------------------
extern "C" void kernel_launch(void* const* d_in, const int* in_sizes, int n_in,
                              void* d_out, int out_size, void* d_ws,
                              size_t ws_size, hipStream_t stream) {
    const float* y = (const float*)d_in[0];
    const float* w = (const float*)d_in[1];
    const float* eps = (const float*)d_in[2];
    const float* lip = (const float*)d_in[3];
    float* out = (float*)d_out;

    char* ws = (char*)d_ws;
    int* jv = (int*)ws;
    float* ymax = (float*)(ws + 4096);
    float* wnorm = (float*)(ws + 8192);
    float* part = (float*)(ws + 16384);
    short* wbf = (short*)(ws + 524288);

    void* args[] = {(void*)&y, (void*)&w, (void*)&eps, (void*)&lip,
                    (void*)&jv, (void*)&ymax, (void*)&wnorm, (void*)&wbf,
                    (void*)&part, (void*)&out};
    hipLaunchCooperativeKernel((const void*)k_fused, dim3(256), dim3(256),
                               args, 0, stream);
}

// Round 3
// 86.038 us; speedup vs baseline: 2.0146x; 2.0146x over previous
//
#include <hip/hip_runtime.h>
#include <math.h>

#define B_SZ 1024
#define C_SZ 1000
#define H_SZ 512

// ws layout (bytes):
//   [0,      4096)   int      jv[1024]       argmax index per batch row
//   [4096,   8192)   float    ymax[1024]     row max of y
//   [8192,  12288)   float    wnorm[1000]    ||w_c||^2 (fp32)
//   [12288,  12352)  int      cnt[16]        per-row-strip completion counters
//   [16384,  81920)  float    part[16][1024] per-bx-strip row maxes
//   [524288,+1MB)    short    wbf[1000*512]  bf16 copy of w

typedef __attribute__((ext_vector_type(8))) short bf16x8;
typedef __attribute__((ext_vector_type(4))) float f32x4;

// ---------------------------------------------------------------------------
// K1 prep, role by blockIdx.x:
//   [0,250):    wnorm + f32->bf16 convert, 4 w-rows per block (1 wave/row)
//   [250,1274): argmax/max of one y row + coalesced y->out copy
//   block 250 additionally zeroes cnt[16] (ws is re-poisoned each iteration)
__global__ __launch_bounds__(256) void k_prep(
    const float* __restrict__ y, const float* __restrict__ w,
    int* __restrict__ jv, float* __restrict__ ymax,
    float* __restrict__ wnorm, short* __restrict__ wbf,
    int* __restrict__ cnt, float* __restrict__ out) {
    const int r = blockIdx.x;
    const int tid = threadIdx.x;
    if (r < 250) {
        const int wave = tid >> 6, lane = tid & 63;
        const int c = r * 4 + wave;
        const float* row = w + c * H_SZ;
        float4 a = *(const float4*)(row + lane * 8);
        float4 b = *(const float4*)(row + lane * 8 + 4);
        float f[8] = {a.x, a.y, a.z, a.w, b.x, b.y, b.z, b.w};
        unsigned short u[8];
        float s = 0.f;
#pragma unroll
        for (int i = 0; i < 8; ++i) {
            s += f[i] * f[i];
            unsigned v = __float_as_uint(f[i]);
            v += 0x7fffu + ((v >> 16) & 1u);  // RNE
            u[i] = (unsigned short)(v >> 16);
        }
        uint4 pk;
        pk.x = (unsigned)u[0] | ((unsigned)u[1] << 16);
        pk.y = (unsigned)u[2] | ((unsigned)u[3] << 16);
        pk.z = (unsigned)u[4] | ((unsigned)u[5] << 16);
        pk.w = (unsigned)u[6] | ((unsigned)u[7] << 16);
        *(uint4*)(wbf + c * H_SZ + lane * 8) = pk;
#pragma unroll
        for (int off = 32; off; off >>= 1) s += __shfl_down(s, off, 64);
        if (lane == 0) wnorm[c] = s;
    } else {
        const int b = r - 250;
        if (b == 0 && tid < 16) cnt[tid] = 0;  // K2 finisher counters
        const float* yrow = y + b * C_SZ;
        float* orow = out + b * (C_SZ + 1);
        float best = -INFINITY;
        int bidx = 0x7fffffff;
        if (tid < 250) {
            float4 v = *(const float4*)(yrow + tid * 4);
            float e[4] = {v.x, v.y, v.z, v.w};
#pragma unroll
            for (int i = 0; i < 4; ++i) {
                orow[tid * 4 + i] = e[i];
                if (e[i] > best) { best = e[i]; bidx = tid * 4 + i; }
            }
        }
        const int lane = tid & 63;
#pragma unroll
        for (int off = 32; off; off >>= 1) {
            float ov = __shfl_down(best, off, 64);
            int oi = __shfl_down(bidx, off, 64);
            if (ov > best || (ov == best && oi < bidx)) { best = ov; bidx = oi; }
        }
        __shared__ float sv[4];
        __shared__ int si[4];
        if (lane == 0) { sv[tid >> 6] = best; si[tid >> 6] = bidx; }
        __syncthreads();
        if (tid == 0) {
            float bv = sv[0]; int bi = si[0];
#pragma unroll
            for (int k = 1; k < 4; ++k) {
                if (sv[k] > bv || (sv[k] == bv && si[k] < bi)) { bv = sv[k]; bi = si[k]; }
            }
            jv[b] = bi;
            ymax[b] = bv;
        }
    }
}

// ---------------------------------------------------------------------------
// K2: gathered bf16 MFMA GEMM + fused epilogue + last-block strip reduce.
// Block 64(b) x 64(c) x K512. A-tile has ZERO cross-wave reuse, so A skips
// LDS: each lane preloads its whole-K A operand (16 x bf16x8 = 64 VGPRs).
// B-tile (4x wave reuse) is LDS-staged, 4 chunks of K=128, register-
// prefetched one chunk ahead. mfma_f32_16x16x32_bf16 (layouts verified).
// Row stride 136 shorts (+8 pad): 2-way bank alias = free.
// After the epilogue, the 16th block of each row-strip (atomic counter)
// reduces the 16 strip partials into the output column — replaces the
// former K3 launch (split-K finisher pattern: release fence + atomic,
// acquire fence before reading part).
#define KC 128          // k elements per chunk
#define RS 136          // LDS row stride in shorts
__global__ __launch_bounds__(256) void k_main(
    const float* __restrict__ y, const short* __restrict__ wbf,
    const float* __restrict__ eps_p, const float* __restrict__ lip_p,
    const int* __restrict__ jv, const float* __restrict__ ymax,
    const float* __restrict__ wnorm, float* __restrict__ part,
    int* __restrict__ cnt, float* __restrict__ out) {
    __shared__ __align__(16) short Bs[64 * RS];
    __shared__ float snj[64];
    __shared__ float sym[64];
    __shared__ int sdone;

    const int t = threadIdx.x;
    const int bx = blockIdx.x, by = blockIdx.y;
    const int b0 = by * 64, c0 = bx * 64;
    const int wv = t >> 6, lane = t & 63;
    const int col = lane & 15, quad = lane >> 4;

    // -------- B chunk-0 prefetch FIRST: it is on the critical path to the
    // first barrier; issuing it ahead of the A-gather chain lets the LDS
    // write's waitcnt retire without draining the A loads.
    const int srow = t >> 2;       // 0..63
    const int sseg = t & 3;
    int crow = c0 + srow; if (crow > C_SZ - 1) crow = C_SZ - 1;
    const short* bgsrc = wbf + crow * H_SZ;

    uint4 pb[4];
#pragma unroll
    for (int p = 0; p < 4; ++p)
        pb[p] = *(const uint4*)(bgsrc + (sseg + p * 4) * 8);

    // epilogue row metadata (read only after the chunk-loop barriers)
    if (t < 64) {
        int j = jv[b0 + t];
        snj[t] = wnorm[j];
        sym[t] = ymax[b0 + t];
    }

    // -------- A: whole-K preload into registers (no LDS round-trip) --------
    // A-frag layout (verified): lane holds row (wv*16+col), 8 contiguous
    // shorts at k = ks*32 + quad*8. areg[k16] covers k16*32 .. +32.
    const int ja = jv[b0 + wv * 16 + col];
    const short* ag = wbf + ja * H_SZ + quad * 8;
    bf16x8 areg[16];
#pragma unroll
    for (int k16 = 0; k16 < 16; ++k16)
        areg[k16] = *(const bf16x8*)(ag + k16 * 32);

    const short* brd = &Bs[col * RS + quad * 8];

    f32x4 acc[4] = {{0.f, 0.f, 0.f, 0.f},
                    {0.f, 0.f, 0.f, 0.f},
                    {0.f, 0.f, 0.f, 0.f},
                    {0.f, 0.f, 0.f, 0.f}};

#pragma unroll   // must unroll: areg[ch*4+ks] needs compile-time indices
    for (int ch = 0; ch < 4; ++ch) {
#pragma unroll
        for (int p = 0; p < 4; ++p)
            *(uint4*)&Bs[srow * RS + (sseg + p * 4) * 8] = pb[p];
        __syncthreads();
        if (ch < 3) {
            const int gbase = (ch + 1) * KC;
#pragma unroll
            for (int p = 0; p < 4; ++p)
                pb[p] = *(const uint4*)(bgsrc + gbase + (sseg + p * 4) * 8);
        }
#pragma unroll
        for (int ks = 0; ks < 4; ++ks) {
            bf16x8 af = areg[ch * 4 + ks];
#pragma unroll
            for (int ct = 0; ct < 4; ++ct) {
                bf16x8 bf = *(const bf16x8*)(brd + ct * 16 * RS + ks * 32);
                acc[ct] =
                    __builtin_amdgcn_mfma_f32_16x16x32_bf16(af, bf, acc[ct], 0, 0, 0);
            }
        }
        __syncthreads();
    }

    // Epilogue. C/D layout: col=lane&15, row=quad*4+reg.
    const float eps = *eps_p;
    const float L = *lip_p;
    const float L2 = L * L;
    float rmax[4];
#pragma unroll
    for (int i = 0; i < 4; ++i) {
        const int br = wv * 16 + quad * 4 + i;
        const int b = b0 + br;
        const float nj = snj[br];
        const float ym = sym[br];
        float m = -INFINITY;
#pragma unroll
        for (int ct = 0; ct < 4; ++ct) {
            const int cc = c0 + ct * 16 + col;
            if (cc < C_SZ) {
                const float yv = y[b * C_SZ + cc];
                const float nc = wnorm[cc];
                const float sq = L2 * (nj + nc - 2.0f * acc[ct][i]);
                const float K = sq > 0.f ? sqrtf(sq) : 0.f;
                const float cand = (yv == ym) ? -INFINITY : yv + eps * K;
                m = fmaxf(m, cand);
            }
        }
        rmax[i] = m;
    }
#pragma unroll
    for (int off = 8; off; off >>= 1)
#pragma unroll
        for (int i = 0; i < 4; ++i)
            rmax[i] = fmaxf(rmax[i], __shfl_xor(rmax[i], off, 64));
    if (col == 0) {
        float* slice = part + bx * B_SZ;
#pragma unroll
        for (int i = 0; i < 4; ++i)
            slice[b0 + wv * 16 + quad * 4 + i] = rmax[i];
    }

    // -------- last-block finisher: reduce 16 strips into out[:, C] --------
    __syncthreads();  // drains vmcnt: all part stores of this block complete
    if (t == 0) {
        __threadfence();  // release: part slice visible agent-wide
        sdone = (atomicAdd(&cnt[by], 1) == 15);
    }
    __syncthreads();
    if (sdone) {
        __threadfence();  // acquire: see all 16 blocks' part slices
        const int r4 = t >> 2, s0 = t & 3;
        const int row = b0 + r4;
        float m = -INFINITY;
#pragma unroll
        for (int s = 0; s < 4; ++s)
            m = fmaxf(m, part[(s0 + s * 4) * B_SZ + row]);
        m = fmaxf(m, __shfl_xor(m, 1, 64));
        m = fmaxf(m, __shfl_xor(m, 2, 64));
        if (s0 == 0) out[row * (C_SZ + 1) + C_SZ] = m;
    }
}

// ---------------------------------------------------------------------------
extern "C" void kernel_launch(void* const* d_in, const int* in_sizes, int n_in,
                              void* d_out, int out_size, void* d_ws,
                              size_t ws_size, hipStream_t stream) {
    const float* y = (const float*)d_in[0];
    const float* w = (const float*)d_in[1];
    const float* eps = (const float*)d_in[2];
    const float* lip = (const float*)d_in[3];
    float* out = (float*)d_out;

    char* ws = (char*)d_ws;
    int* jv = (int*)ws;
    float* ymax = (float*)(ws + 4096);
    float* wnorm = (float*)(ws + 8192);
    int* cnt = (int*)(ws + 12288);
    float* part = (float*)(ws + 16384);
    short* wbf = (short*)(ws + 524288);

    k_prep<<<250 + B_SZ, 256, 0, stream>>>(y, w, jv, ymax, wnorm, wbf, cnt,
                                           out);
    k_main<<<dim3(16, 16), 256, 0, stream>>>(y, wbf, eps, lip, jv, ymax, wnorm,
                                             part, cnt, out);
}

// Round 4
// 78.663 us; speedup vs baseline: 2.2035x; 1.0938x over previous
//
#include <hip/hip_runtime.h>
#include <math.h>

#define B_SZ 1024
#define C_SZ 1000
#define H_SZ 512

// ws layout (bytes):
//   [0,      4096)   int      jv[1024]       argmax index per batch row
//   [4096,   8192)   float    ymax[1024]     row max of y
//   [8192,  12288)   float    wnorm[1000]    ||w_c||^2 (fp32)
//   [16384,  81920)  float    part[16][1024] per-bx-strip row maxes
//   [524288,+1MB)    short    wbf[1000*512]  bf16 copy of w

typedef __attribute__((ext_vector_type(8))) short bf16x8;
typedef __attribute__((ext_vector_type(4))) float f32x4;

// ---------------------------------------------------------------------------
// K1 prep, role by blockIdx.x:
//   [0,250):    wnorm + f32->bf16 convert, 4 w-rows per block (1 wave/row)
//   [250,1274): argmax/max of one y row + coalesced y->out copy
__global__ __launch_bounds__(256) void k_prep(
    const float* __restrict__ y, const float* __restrict__ w,
    int* __restrict__ jv, float* __restrict__ ymax,
    float* __restrict__ wnorm, short* __restrict__ wbf,
    float* __restrict__ out) {
    const int r = blockIdx.x;
    const int tid = threadIdx.x;
    if (r < 250) {
        const int wave = tid >> 6, lane = tid & 63;
        const int c = r * 4 + wave;
        const float* row = w + c * H_SZ;
        float4 a = *(const float4*)(row + lane * 8);
        float4 b = *(const float4*)(row + lane * 8 + 4);
        float f[8] = {a.x, a.y, a.z, a.w, b.x, b.y, b.z, b.w};
        unsigned short u[8];
        float s = 0.f;
#pragma unroll
        for (int i = 0; i < 8; ++i) {
            s += f[i] * f[i];
            unsigned v = __float_as_uint(f[i]);
            v += 0x7fffu + ((v >> 16) & 1u);  // RNE
            u[i] = (unsigned short)(v >> 16);
        }
        uint4 pk;
        pk.x = (unsigned)u[0] | ((unsigned)u[1] << 16);
        pk.y = (unsigned)u[2] | ((unsigned)u[3] << 16);
        pk.z = (unsigned)u[4] | ((unsigned)u[5] << 16);
        pk.w = (unsigned)u[6] | ((unsigned)u[7] << 16);
        *(uint4*)(wbf + c * H_SZ + lane * 8) = pk;
#pragma unroll
        for (int off = 32; off; off >>= 1) s += __shfl_down(s, off, 64);
        if (lane == 0) wnorm[c] = s;
    } else {
        const int b = r - 250;
        const float* yrow = y + b * C_SZ;
        float* orow = out + b * (C_SZ + 1);
        float best = -INFINITY;
        int bidx = 0x7fffffff;
        if (tid < 250) {
            float4 v = *(const float4*)(yrow + tid * 4);
            float e[4] = {v.x, v.y, v.z, v.w};
#pragma unroll
            for (int i = 0; i < 4; ++i) {
                orow[tid * 4 + i] = e[i];
                if (e[i] > best) { best = e[i]; bidx = tid * 4 + i; }
            }
        }
        const int lane = tid & 63;
#pragma unroll
        for (int off = 32; off; off >>= 1) {
            float ov = __shfl_down(best, off, 64);
            int oi = __shfl_down(bidx, off, 64);
            if (ov > best || (ov == best && oi < bidx)) { best = ov; bidx = oi; }
        }
        __shared__ float sv[4];
        __shared__ int si[4];
        if (lane == 0) { sv[tid >> 6] = best; si[tid >> 6] = bidx; }
        __syncthreads();
        if (tid == 0) {
            float bv = sv[0]; int bi = si[0];
#pragma unroll
            for (int k = 1; k < 4; ++k) {
                if (sv[k] > bv || (sv[k] == bv && si[k] < bi)) { bv = sv[k]; bi = si[k]; }
            }
            jv[b] = bi;
            ymax[b] = bv;
        }
    }
}

// ---------------------------------------------------------------------------
// K2: gathered bf16 MFMA GEMM + fused epilogue.
// Block 64(b) x 64(c) x K512. A-tile has ZERO cross-wave reuse (each wave
// owns a disjoint 16 rows), so A skips LDS entirely: each lane preloads its
// whole-K A operand (16 x bf16x8 = 64 VGPRs) up front; the 16 independent
// gathers pipeline and their latency hides under B chunk-0 staging.
// B-tile (4x wave reuse) stays LDS-staged, 4 chunks of K=128, register-
// prefetched one chunk ahead. mfma_f32_16x16x32_bf16 (layouts verified in
// the prior session's R2-R4). Row stride 136 shorts (+8 pad): 2-way = free.
#define KC 128          // k elements per chunk
#define RS 136          // LDS row stride in shorts
__global__ __launch_bounds__(256) void k_main(
    const float* __restrict__ y, const short* __restrict__ wbf,
    const float* __restrict__ eps_p, const float* __restrict__ lip_p,
    const int* __restrict__ jv, const float* __restrict__ ymax,
    const float* __restrict__ wnorm, float* __restrict__ part) {
    __shared__ __align__(16) short Bs[64 * RS];
    __shared__ float snj[64];
    __shared__ float sym[64];

    const int t = threadIdx.x;
    const int bx = blockIdx.x, by = blockIdx.y;
    const int b0 = by * 64, c0 = bx * 64;

    // epilogue row metadata (read only after the chunk-loop barriers)
    if (t < 64) {
        int j = jv[b0 + t];
        snj[t] = wnorm[j];
        sym[t] = ymax[b0 + t];
    }

    const int wv = t >> 6, lane = t & 63;
    const int col = lane & 15, quad = lane >> 4;

    // -------- A: whole-K preload into registers (no LDS round-trip) --------
    // A-frag layout (verified): lane holds row (wv*16+col), 8 contiguous
    // shorts at k = ks*32 + quad*8. areg[k16] covers k16*32 .. +32.
    const int ja = jv[b0 + wv * 16 + col];
    const short* ag = wbf + ja * H_SZ + quad * 8;
    bf16x8 areg[16];
#pragma unroll
    for (int k16 = 0; k16 < 16; ++k16)
        areg[k16] = *(const bf16x8*)(ag + k16 * 32);

    // -------- B: LDS staging, 4 threads per row, 4 passes of 16B ----------
    const int srow = t >> 2;       // 0..63
    const int sseg = t & 3;
    int crow = c0 + srow; if (crow > C_SZ - 1) crow = C_SZ - 1;
    const short* bgsrc = wbf + crow * H_SZ;

    uint4 pb[4];
#pragma unroll
    for (int p = 0; p < 4; ++p)
        pb[p] = *(const uint4*)(bgsrc + (sseg + p * 4) * 8);

    const short* brd = &Bs[col * RS + quad * 8];

    f32x4 acc[4] = {{0.f, 0.f, 0.f, 0.f},
                    {0.f, 0.f, 0.f, 0.f},
                    {0.f, 0.f, 0.f, 0.f},
                    {0.f, 0.f, 0.f, 0.f}};

#pragma unroll   // must unroll: areg[ch*4+ks] needs compile-time indices
    for (int ch = 0; ch < 4; ++ch) {
        // write prefetched B chunk to LDS
#pragma unroll
        for (int p = 0; p < 4; ++p)
            *(uint4*)&Bs[srow * RS + (sseg + p * 4) * 8] = pb[p];
        __syncthreads();
        // prefetch next B chunk (global loads overlap MFMA compute below)
        if (ch < 3) {
            const int gbase = (ch + 1) * KC;
#pragma unroll
            for (int p = 0; p < 4; ++p)
                pb[p] = *(const uint4*)(bgsrc + gbase + (sseg + p * 4) * 8);
        }
        // compute: 4 k-steps of 32 per chunk; A comes straight from VGPRs
#pragma unroll
        for (int ks = 0; ks < 4; ++ks) {
            bf16x8 af = areg[ch * 4 + ks];
#pragma unroll
            for (int ct = 0; ct < 4; ++ct) {
                bf16x8 bf = *(const bf16x8*)(brd + ct * 16 * RS + ks * 32);
                acc[ct] =
                    __builtin_amdgcn_mfma_f32_16x16x32_bf16(af, bf, acc[ct], 0, 0, 0);
            }
        }
        __syncthreads();  // compute done before next chunk's LDS overwrite
    }

    // Epilogue. C/D layout: col=lane&15, row=quad*4+reg.
    const float eps = *eps_p;
    const float L = *lip_p;
    const float L2 = L * L;
    float rmax[4];
#pragma unroll
    for (int i = 0; i < 4; ++i) {
        const int br = wv * 16 + quad * 4 + i;
        const int b = b0 + br;
        const float nj = snj[br];
        const float ym = sym[br];
        float m = -INFINITY;
#pragma unroll
        for (int ct = 0; ct < 4; ++ct) {
            const int cc = c0 + ct * 16 + col;
            if (cc < C_SZ) {
                const float yv = y[b * C_SZ + cc];
                const float nc = wnorm[cc];
                const float sq = L2 * (nj + nc - 2.0f * acc[ct][i]);
                const float K = sq > 0.f ? sqrtf(sq) : 0.f;
                const float cand = (yv == ym) ? -INFINITY : yv + eps * K;
                m = fmaxf(m, cand);
            }
        }
        rmax[i] = m;
    }
    // max over the 16 cols (bits 0..3 of lane)
#pragma unroll
    for (int off = 8; off; off >>= 1)
#pragma unroll
        for (int i = 0; i < 4; ++i)
            rmax[i] = fmaxf(rmax[i], __shfl_xor(rmax[i], off, 64));
    if (col == 0) {
        float* slice = part + bx * B_SZ;
#pragma unroll
        for (int i = 0; i < 4; ++i)
            slice[b0 + wv * 16 + quad * 4 + i] = rmax[i];
    }
}

// ---------------------------------------------------------------------------
// K3: reduce the 16 per-strip partial maxes into the last output column.
__global__ void k_final(const float* __restrict__ part,
                        float* __restrict__ out) {
    int b = blockIdx.x * 256 + threadIdx.x;
    if (b >= B_SZ) return;
    float m = -INFINITY;
#pragma unroll
    for (int s = 0; s < 16; ++s) m = fmaxf(m, part[s * B_SZ + b]);
    out[b * (C_SZ + 1) + C_SZ] = m;
}

// ---------------------------------------------------------------------------
extern "C" void kernel_launch(void* const* d_in, const int* in_sizes, int n_in,
                              void* d_out, int out_size, void* d_ws,
                              size_t ws_size, hipStream_t stream) {
    const float* y = (const float*)d_in[0];
    const float* w = (const float*)d_in[1];
    const float* eps = (const float*)d_in[2];
    const float* lip = (const float*)d_in[3];
    float* out = (float*)d_out;

    char* ws = (char*)d_ws;
    int* jv = (int*)ws;
    float* ymax = (float*)(ws + 4096);
    float* wnorm = (float*)(ws + 8192);
    float* part = (float*)(ws + 16384);
    short* wbf = (short*)(ws + 524288);

    k_prep<<<250 + B_SZ, 256, 0, stream>>>(y, w, jv, ymax, wnorm, wbf, out);
    k_main<<<dim3(16, 16), 256, 0, stream>>>(y, wbf, eps, lip, jv, ymax, wnorm,
                                             part);
    k_final<<<(B_SZ + 255) / 256, 256, 0, stream>>>(part, out);
}